// Round 7
// baseline (40.309 us; speedup 1.0000x reference)
//
#include <hip/hip_runtime.h>

#define VOCAB 30522
#define SEQ 512
#define NSLICE 16                  // vocab sixteenths per row, one per wave-task
#define SENT 1908                  // entries per slice (last slice: 1902)
#define SWORDS (SENT / 2)          // 954 packed uint32 words (2 x uint16 counts)
#define WPB 4                      // waves per block

// Barrier-free: each WAVE owns one (row, slice) task with a private LDS slice.
// Per-wave DS ops are in-order, so zero -> scatter -> read needs no barrier.
__global__ __launch_bounds__(256) void bow_wave_kernel(const int* __restrict__ ids,
                                                       float* __restrict__ out) {
    __shared__ unsigned int hist[WPB][SWORDS];   // 15264 B -> 8 blocks/CU

    const int wid  = threadIdx.x >> 6;
    const int lane = threadIdx.x & 63;
    const int task = blockIdx.x * WPB + wid;     // 0 .. B*NSLICE-1
    const int row  = task >> 4;
    const int six  = task & (NSLICE - 1);

    unsigned int* h = hist[wid];

    // Zero own slice (15 words/lane).
    for (int i = lane; i < SWORDS; i += 64) h[i] = 0u;

    // Load the row's 512 tokens: two int4 loads per lane (1 KB per wave each).
    const int* rbase = ids + (size_t)row * SEQ;
    const int4 ta = *reinterpret_cast<const int4*>(rbase + 4 * lane);
    const int4 tb = *reinterpret_cast<const int4*>(rbase + 256 + 4 * lane);
    int tok[8] = {ta.x, ta.y, ta.z, ta.w, tb.x, tb.y, tb.z, tb.w};

    // First-pad cutoff: min position of any pad token, wave-reduced.
    int m = SEQ;
#pragma unroll
    for (int j = 0; j < 8; ++j) {
        const int p = (j < 4) ? (4 * lane + j) : (256 + 4 * lane + (j - 4));
        if (tok[j] == 0) m = min(m, p);
    }
#pragma unroll
    for (int off = 32; off; off >>= 1) m = min(m, __shfl_xor(m, off, 64));

    // Scatter tokens belonging to this slice. uint16 halves never carry (<=512/row).
    const int lo = six * SENT;
    const int ne = (six == NSLICE - 1) ? (VOCAB - lo) : SENT;   // 1902 last
#pragma unroll
    for (int j = 0; j < 8; ++j) {
        const int p = (j < 4) ? (4 * lane + j) : (256 + 4 * lane + (j - 4));
        const int r = tok[j] - lo;
        if (p < m && (unsigned)r < (unsigned)ne)
            atomicAdd(&h[r >> 1], 1u << ((r & 1) << 4));
    }

    // Stream the slice out, coalesced float2 stores (base bytes = row*122088 +
    // six*7632, both multiples of 8). No barrier: same-wave DS ops are ordered.
    const int nw = (six == NSLICE - 1) ? (VOCAB - lo) / 2 : SWORDS;  // 951 last
    float* obase = out + (size_t)row * VOCAB + lo;
    for (int i = lane; i < nw; i += 64) {
        const unsigned int w = h[i];
        float2 f = make_float2((float)(w & 0xFFFFu), (float)(w >> 16));
        *reinterpret_cast<float2*>(obase + 2 * i) = f;
    }
}

extern "C" void kernel_launch(void* const* d_in, const int* in_sizes, int n_in,
                              void* d_out, int out_size, void* d_ws, size_t ws_size,
                              hipStream_t stream) {
    const int* ids = (const int*)d_in[0];
    float* out     = (float*)d_out;
    const int B    = in_sizes[0] / SEQ;   // 2048

    bow_wave_kernel<<<(B * NSLICE) / WPB, 256, 0, stream>>>(ids, out);
}

// Round 8
// 38.316 us; speedup vs baseline: 1.0520x; 1.0520x over previous
//
#include <hip/hip_runtime.h>

#define VOCAB 30522
#define SEQ 512
#define NQ 4                       // vocab quarters per row
#define QENT 7632                  // vocab entries per quarter (last covers 7626)
#define QWORDS (QENT / 2)          // 3816 packed uint32 words (2 x uint16 counts)

__global__ __launch_bounds__(256) void bow_row_kernel(const int* __restrict__ ids,
                                                      float* __restrict__ out) {
    __shared__ unsigned int hist[QWORDS];   // 15264 B -> 8 blocks/CU (thread-limited)
    __shared__ int s_cut;

    const int b   = blockIdx.x;    // one block per row
    const int tid = threadIdx.x;

    if (tid == 0) s_cut = SEQ;

    // Issue the row's token loads (512 tokens, 2/thread); zero the quarter-0
    // histogram under the load latency shadow.
    const int t0 = ids[(size_t)b * SEQ + tid];
    const int t1 = ids[(size_t)b * SEQ + tid + 256];

    for (int i = tid; i < QWORDS; i += 256) hist[i] = 0u;
    __syncthreads();

    // First-pad cutoff: token t counts iff t < min index of any pad token.
    if (t0 == 0) atomicMin(&s_cut, tid);
    if (t1 == 0) atomicMin(&s_cut, tid + 256);
    __syncthreads();

    const int  cut = s_cut;
    const bool v0  = tid < cut;
    const bool v1  = tid + 256 < cut;

    float* orow = out + (size_t)b * VOCAB;

    for (int q = 0; q < NQ; ++q) {
        const int lo = q * QENT;

        // Scatter this quarter's tokens. uint16 halves never carry (<=512/row).
        if (v0) {
            const int r = t0 - lo;
            if ((unsigned)r < (unsigned)QENT)
                atomicAdd(&hist[r >> 1], 1u << ((r & 1) << 4));
        }
        if (v1) {
            const int r = t1 - lo;
            if ((unsigned)r < (unsigned)QENT)
                atomicAdd(&hist[r >> 1], 1u << ((r & 1) << 4));
        }
        __syncthreads();

        // Stream the quarter out (regular stores — NT was a 2x regression, R5)
        // and fold the re-zero into the same pass. Base is always 8B-aligned.
        const int nw = (q == NQ - 1) ? (VOCAB - (NQ - 1) * QENT) / 2 : QWORDS; // 3813 last
        float* obase = orow + lo;
        for (int i = tid; i < nw; i += 256) {
            const unsigned int w = hist[i];
            hist[i] = 0u;          // re-zero for next quarter in the same pass
            float2 f = make_float2((float)(w & 0xFFFFu), (float)(w >> 16));
            *reinterpret_cast<float2*>(obase + 2 * i) = f;
        }

        if (q < NQ - 1) __syncthreads();   // zero visible before next scatter
    }
}

extern "C" void kernel_launch(void* const* d_in, const int* in_sizes, int n_in,
                              void* d_out, int out_size, void* d_ws, size_t ws_size,
                              hipStream_t stream) {
    const int* ids = (const int*)d_in[0];
    float* out     = (float*)d_out;
    const int B    = in_sizes[0] / SEQ;   // 2048

    bow_row_kernel<<<B, 256, 0, stream>>>(ids, out);
}